// Round 10
// baseline (83.319 us; speedup 1.0000x reference)
//
#include <hip/hip_runtime.h>

// Embedder: counts = scatter_add(one_hot(tokens)) -> (B, DEPTH) float32
// B=1024, S=200, DEPTH=100000. Output = 409.6 MB -> pure write-BW bound.
//
// Persistent pipelined design, v2. R9's leak: per-unit token loads were
// issued AFTER the previous unit's stores, so waiting for them forced
// s_waitcnt vmcnt(0) -> full store-stream drain every unit (vmcnt waits
// count from the newest op). Fix: preload ALL 10 units' (token,value)
// pairs into registers in the prologue, BEFORE any store is issued.
// The unit loop then contains ZERO vmem waits:
//   scatter (regs -> ds_add_f32) -> [lgkm barrier] ->
//   fused readback {d=a4[i]; global_store d; a4[i]=0} -> [lgkm barrier]
// Same-thread same-address DS ops are in-order, so read+rezero fuse into
// one phase (drops a barrier). Global stores are never waited on; pacing
// is pure store-queue backpressure — same regime as the 6.6 TB/s fill.
// 1024 blocks = 4/CU persistent, 40 KB LDS each (160 KB/CU exactly).

#define EMB_DEPTH 100000
#define EMB_SEQ   200
#define NSEG      10
#define SEGF      (EMB_DEPTH / NSEG)     // 10000 floats = 40,000 B
#define SEGF4     (SEGF / 4)             // 2500 float4
#define KITER     ((SEGF4 + 255) / 256)  // 10
#define NBLOCKS   1024
#define UPB       10                     // units per block

__global__ __launch_bounds__(256) void embedder_pipe2_kernel(
    const int*   __restrict__ tokens,     // (B, S) int32
    const float* __restrict__ on_values,  // (B, S) float32
    float*       __restrict__ out)        // (B, DEPTH) float32
{
    __shared__ float acc[SEGF];           // 40,000 B
    float4* a4 = reinterpret_cast<float4*>(acc);

    const int tid = threadIdx.x;
    const int blk = blockIdx.x;

    // ---- prologue: preload all units' (token,value) into registers ----
    // 20 VGPRs. All loads precede all stores -> every later wait on them
    // is a counted vmcnt(N), never a drain.
    int   tok[UPB];
    float val[UPB];
    #pragma unroll
    for (int it = 0; it < UPB; ++it) {
        const int u   = it * NBLOCKS + blk;
        const int row = u / NSEG;
        tok[it] = -1; val[it] = 0.f;
        if (tid < EMB_SEQ) {
            tok[it] = tokens[(size_t)row * EMB_SEQ + tid];
            val[it] = on_values[(size_t)row * EMB_SEQ + tid];
        }
    }

    // ---- initial zero of the accumulator ----
    #pragma unroll
    for (int k = 0; k < KITER; ++k) {
        const int i = k * 256 + tid;
        if (i < SEGF4) a4[i] = make_float4(0.f, 0.f, 0.f, 0.f);
    }
    asm volatile("s_waitcnt lgkmcnt(0)" ::: "memory");
    __builtin_amdgcn_s_barrier();

    // ---- unit loop: no vmem waits anywhere ----
    #pragma unroll
    for (int it = 0; it < UPB; ++it) {
        const int u   = it * NBLOCKS + blk;
        const int row = u / NSEG;
        const int lo  = (u - row * NSEG) * SEGF;

        // Scatter from registers (native ds_add_f32).
        if (tid < EMB_SEQ) {
            const unsigned rel = (unsigned)(tok[it] - lo);
            if (rel < (unsigned)SEGF) atomicAdd(&acc[rel], val[it]);
        }
        asm volatile("s_waitcnt lgkmcnt(0)" ::: "memory");
        __builtin_amdgcn_s_barrier();

        // Fused readback + store + re-zero. Same thread reads and
        // re-zeros the same address; per-wave DS ops are in-order.
        float4* o4 = reinterpret_cast<float4*>(out + (size_t)u * SEGF);
        #pragma unroll
        for (int k = 0; k < KITER; ++k) {
            const int i = k * 256 + tid;
            if (i < SEGF4) {
                const float4 d = a4[i];
                o4[i] = d;                              // never waited on
                a4[i] = make_float4(0.f, 0.f, 0.f, 0.f);
            }
        }
        asm volatile("s_waitcnt lgkmcnt(0)" ::: "memory");
        __builtin_amdgcn_s_barrier();
    }
}

extern "C" void kernel_launch(void* const* d_in, const int* in_sizes, int n_in,
                              void* d_out, int out_size, void* d_ws, size_t ws_size,
                              hipStream_t stream) {
    const int*   tokens    = (const int*)  d_in[0];
    const float* on_values = (const float*)d_in[1];
    float*       out       = (float*)      d_out;

    embedder_pipe2_kernel<<<NBLOCKS, 256, 0, stream>>>(tokens, on_values, out);
}